// Round 7
// baseline (221.993 us; speedup 1.0000x reference)
//
#include <hip/hip_runtime.h>
#include <hip/hip_bf16.h>

typedef __attribute__((ext_vector_type(8))) short short8;
typedef __attribute__((ext_vector_type(4))) float f32x4;

using bf16 = __hip_bfloat16;

#define L_SEQ 2048
#define NB 2
#define DM 1024
#define NH 16
#define NKV 4
#define HDIM 64
#define CAPV 50.0f
#define CH 8      // k-tiles per split-K chunk
#define NCHMAX 4  // max chunks (32 k-tiles / 8)

#if __has_builtin(__builtin_amdgcn_exp2f)
#define EXP2(x) __builtin_amdgcn_exp2f(x)
#else
#define EXP2(x) exp2f(x)
#endif

__device__ __forceinline__ unsigned short f2bs(float f) {
  bf16 h = __float2bfloat16(f);
  return __builtin_bit_cast(unsigned short, h);
}

__device__ __forceinline__ float bs2f(unsigned short u) {
  return __bfloat162float(__builtin_bit_cast(bf16, u));
}

__device__ __forceinline__ void gload_lds16(const void* g, void* l) {
  __builtin_amdgcn_global_load_lds(
      (const __attribute__((address_space(1))) void*)g,
      (__attribute__((address_space(3))) void*)l, 16, 0, 0);
}

// ---------------- x -> bf16 ----------------
__global__ void k_cvt_x(const float* __restrict__ x, ushort* __restrict__ xb) {
  int i = (blockIdx.x * blockDim.x + threadIdx.x) * 4;
  float4 v = *reinterpret_cast<const float4*>(x + i);
  ushort4 o = make_ushort4(f2bs(v.x), f2bs(v.y), f2bs(v.z), f2bs(v.w));
  *reinterpret_cast<ushort4*>(xb + i) = o;
}

// ---------------- all W[K][N] f32 -> Wt[N][K] bf16, one launch ----------------
__global__ void k_transpose_all(const float* __restrict__ Wq, const float* __restrict__ Wk,
                                const float* __restrict__ Wv, const float* __restrict__ Wo,
                                bf16* __restrict__ wqt, bf16* __restrict__ wkt,
                                bf16* __restrict__ wvt, bf16* __restrict__ wot) {
  __shared__ float tile[32][33];
  const int z = blockIdx.z;
  const float* W = (z == 0) ? Wq : (z == 1) ? Wk : (z == 2) ? Wv : Wo;
  bf16* Wt = (z == 0) ? wqt : (z == 1) ? wkt : (z == 2) ? wvt : wot;
  const int Ncols = (z == 1 || z == 2) ? 256 : 1024;
  const int bx = blockIdx.x * 32;
  if (bx >= Ncols) return;
  const int by = blockIdx.y * 32;
  const int tx = threadIdx.x, ty = threadIdx.y;
  #pragma unroll
  for (int j = 0; j < 32; j += 8)
    tile[ty + j][tx] = W[(size_t)(by + ty + j) * Ncols + bx + tx];
  __syncthreads();
  #pragma unroll
  for (int j = 0; j < 32; j += 8)
    Wt[(size_t)(bx + ty + j) * 1024 + by + tx] = __float2bfloat16(tile[tx][ty + j]);
}

// ---------------- GEMM: C[M,N] = A[M,K] @ Bt[N,K]^T + bias ----------------
// BM=64, BN=128, BK=64. LDS granule-XOR swizzled (pre-swizzled gload src).
// OUT_MODE: 0 = bf16 row-major, 1 = f32 row-major, 2 = bf16 transposed Vt,
//           3 = fused KV: col<256 -> kp row-major (bias), col>=256 -> Vt (bias2)
template<int OUT_MODE>
__global__ __launch_bounds__(256) void k_gemm(const bf16* __restrict__ A,
                                              const bf16* __restrict__ Bt,
                                              const float* __restrict__ bias,
                                              const float* __restrict__ bias2,
                                              void* __restrict__ Cout,
                                              void* __restrict__ Cout2,
                                              int M, int Ncols, int K) {
  __shared__ __align__(16) bf16 As[64 * 64];
  __shared__ __align__(16) bf16 Bs[128 * 64];
  const int t = threadIdx.x;
  const int lane = t & 63;
  const int w = t >> 6;
  const int wr = w >> 1, wc = w & 1;
  const int m0 = blockIdx.y * 64, n0 = blockIdx.x * 128;
  const int lr = lane & 15, lg = lane >> 4;

  f32x4 acc[2][4];
  #pragma unroll
  for (int m = 0; m < 2; ++m)
    #pragma unroll
    for (int n = 0; n < 4; ++n)
      acc[m][n] = f32x4{0.f, 0.f, 0.f, 0.f};

  for (int kt = 0; kt < K; kt += 64) {
    #pragma unroll
    for (int p = 0; p < 2; ++p) {
      const int Gb = p * 256 + w * 64;
      const int G = Gb + lane;
      const int row = G >> 3, gc = G & 7;
      gload_lds16(&A[(size_t)(m0 + row) * K + kt + ((gc ^ (row & 7)) * 8)], &As[Gb * 8]);
    }
    #pragma unroll
    for (int p = 0; p < 4; ++p) {
      const int Gb = p * 256 + w * 64;
      const int G = Gb + lane;
      const int row = G >> 3, gc = G & 7;
      gload_lds16(&Bt[(size_t)(n0 + row) * K + kt + ((gc ^ (row & 7)) * 8)], &Bs[Gb * 8]);
    }
    __syncthreads();
    #pragma unroll
    for (int ks = 0; ks < 2; ++ks) {
      short8 af[2], bfr[4];
      #pragma unroll
      for (int m = 0; m < 2; ++m) {
        const int row = wr * 32 + m * 16 + lr;
        af[m] = *reinterpret_cast<const short8*>(&As[row * 64 + (((ks * 4 + lg) ^ (row & 7)) * 8)]);
      }
      #pragma unroll
      for (int n = 0; n < 4; ++n) {
        const int row = wc * 64 + n * 16 + lr;
        bfr[n] = *reinterpret_cast<const short8*>(&Bs[row * 64 + (((ks * 4 + lg) ^ (row & 7)) * 8)]);
      }
      #pragma unroll
      for (int m = 0; m < 2; ++m)
        #pragma unroll
        for (int n = 0; n < 4; ++n)
          acc[m][n] = __builtin_amdgcn_mfma_f32_16x16x32_bf16(af[m], bfr[n], acc[m][n], 0, 0, 0);
    }
    __syncthreads();
  }

  #pragma unroll
  for (int m = 0; m < 2; ++m) {
    const int row = m0 + wr * 32 + m * 16 + lg * 4;
    #pragma unroll
    for (int n = 0; n < 4; ++n) {
      const int col = n0 + wc * 64 + n * 16 + lr;
      if (OUT_MODE == 2) {
        const float bv = bias[col];
        const int bb = row >> 11, l = row & 2047;
        ushort4 o;
        o.x = f2bs(acc[m][n][0] + bv);
        o.y = f2bs(acc[m][n][1] + bv);
        o.z = f2bs(acc[m][n][2] + bv);
        o.w = f2bs(acc[m][n][3] + bv);
        *reinterpret_cast<ushort4*>(
            &reinterpret_cast<bf16*>(Cout)[((size_t)bb * 256 + col) * L_SEQ + l]) = o;
      } else if (OUT_MODE == 3) {
        if (col < 256) {  // block-uniform branch (n0 in {0,128})
          const float bv = bias[col];
          #pragma unroll
          for (int r = 0; r < 4; ++r)
            reinterpret_cast<bf16*>(Cout)[(size_t)(row + r) * 256 + col] =
                __float2bfloat16(acc[m][n][r] + bv);
        } else {
          const int d = col - 256;
          const float bv = bias2[d];
          const int bb = row >> 11, l = row & 2047;
          ushort4 o;
          o.x = f2bs(acc[m][n][0] + bv);
          o.y = f2bs(acc[m][n][1] + bv);
          o.z = f2bs(acc[m][n][2] + bv);
          o.w = f2bs(acc[m][n][3] + bv);
          *reinterpret_cast<ushort4*>(
              &reinterpret_cast<bf16*>(Cout2)[((size_t)bb * 256 + d) * L_SEQ + l]) = o;
        }
      } else {
        const float bv = bias[col];
        #pragma unroll
        for (int r = 0; r < 4; ++r) {
          const float v = acc[m][n][r] + bv;
          if (OUT_MODE == 1)
            reinterpret_cast<float*>(Cout)[(size_t)(row + r) * Ncols + col] = v;
          else
            reinterpret_cast<bf16*>(Cout)[(size_t)(row + r) * Ncols + col] = __float2bfloat16(v);
        }
      }
    }
  }
}

// ---------------- RMSNorm + RoPE + layout (b,h,l,d) for q,k ----------------
__global__ __launch_bounds__(256) void k_rmsrope(
    const bf16* __restrict__ qp, const bf16* __restrict__ kp,
    const float* __restrict__ qg, const float* __restrict__ kg,
    const float* __restrict__ rc, const float* __restrict__ rs,
    bf16* __restrict__ qb, bf16* __restrict__ kb) {
  const int slot = blockIdx.x * 4 + (threadIdx.x >> 6);
  const int lane = threadIdx.x & 63;
  const int b = slot / (L_SEQ * 20);
  const int rem = slot % (L_SEQ * 20);
  const int l = rem / 20;
  const int s = rem % 20;

  const bool isq = (s < 16);
  const int h = isq ? s : s - 16;
  const bf16* src = isq ? qp : kp;
  const int cols = isq ? NH * HDIM : NKV * HDIM;
  float val = __bfloat162float(src[((size_t)b * L_SEQ + l) * cols + h * HDIM + lane]);
  float ss = val * val;
  #pragma unroll
  for (int o = 1; o < 64; o <<= 1) ss += __shfl_xor(ss, o, 64);
  const float inv = rsqrtf(ss * (1.0f / 64.0f) + 1e-6f);
  const float* g = isq ? qg : kg;
  const float tv = val * inv * g[h * HDIM + lane];
  const float partner = __shfl_xor(tv, 32, 64);
  const float rot = (lane < 32) ? -partner : partner;
  const float out = tv * rc[l * HDIM + lane] + rot * rs[l * HDIM + lane];
  bf16* dst = isq ? qb : kb;
  const int heads = isq ? NH : NKV;
  dst[(((size_t)b * heads + h) * L_SEQ + l) * HDIM + lane] = __float2bfloat16(out);
}

// ---------------- Flash attention, chunked split-K ------------------
// Fixed-shift base-2 softmax => linear over k-tiles. Each (qt, bh, chunk)
// block processes up to CH=8 k-tiles; ~2560 active blocks (causal) vs
// residency capacity ~1536 => queue-refill load-balances. Inactive chunks
// exit immediately. Partials: bf16 O-numerator + f32 denominator per slot.
__global__ __launch_bounds__(256) void k_attn(
    const bf16* __restrict__ qb, const bf16* __restrict__ kb,
    const bf16* __restrict__ vt, bf16* __restrict__ pO,
    float* __restrict__ pd, const int* __restrict__ causal_flag) {
  __shared__ __align__(16) bf16 Ks[2][64 * 64];
  __shared__ __align__(16) bf16 Ps[4 * 16 * 64];

  const int t = threadIdx.x, lane = t & 63, w = t >> 6;
  const int lr = lane & 15, lg = lane >> 4;
  const int bh = blockIdx.y;
  const int b = bh >> 4, h = bh & 15;
  const int kvh = h >> 2;
  const bool causal = (*causal_flag) != 0;
  const int qt = 31 - (int)blockIdx.x;   // heavy q-tiles first
  const int q0 = qt * 64;
  const int nkt = causal ? (qt + 1) : 32;
  const int chunk = blockIdx.z;
  const int lo = chunk * CH;
  if (lo >= nkt) return;                 // inactive chunk (wave-uniform)
  const int hi = min(lo + CH, nkt);
  const int row0 = q0 + w * 16;

  const bf16* kbase = kb + ((size_t)b * NKV + kvh) * L_SEQ * HDIM;
  const bf16* vbase = vt + ((size_t)b * NKV + kvh) * HDIM * L_SEQ;

  const bf16* qrow = qb + (((size_t)bh) * L_SEQ + row0 + lr) * HDIM;
  short8 qf[2];
  qf[0] = *reinterpret_cast<const short8*>(qrow + lg * 8);
  qf[1] = *reinterpret_cast<const short8*>(qrow + 32 + lg * 8);

  f32x4 oacc[4];
  #pragma unroll
  for (int n = 0; n < 4; ++n) oacc[n] = f32x4{0.f, 0.f, 0.f, 0.f};
  float plt[4];  // per-lane partial softmax denominators
  #pragma unroll
  for (int r = 0; r < 4; ++r) plt[r] = 0.f;

  {
    #pragma unroll
    for (int i = 0; i < 2; ++i) {
      const int Gbase = i * 256 + w * 64;
      const int G = Gbase + lane;
      const int row = G >> 3, pg = G & 7;
      gload_lds16(kbase + (size_t)(lo * 64 + row) * HDIM + ((pg ^ (row & 7)) * 8),
                  &Ks[0][Gbase * 8]);
    }
  }
  int cur = 0;

  for (int kt = lo; kt < hi; ++kt) {
    __syncthreads();  // buf[cur] ready

    if (kt + 1 < hi) {
      const int k0n = (kt + 1) * 64;
      #pragma unroll
      for (int i = 0; i < 2; ++i) {
        const int Gbase = i * 256 + w * 64;
        const int G = Gbase + lane;
        const int row = G >> 3, pg = G & 7;
        gload_lds16(kbase + (size_t)(k0n + row) * HDIM + ((pg ^ (row & 7)) * 8),
                    &Ks[cur ^ 1][Gbase * 8]);
      }
    }

    // V fragments from global (L2-resident), issued early, consumed at PV
    short8 vf[2][4];
    #pragma unroll
    for (int ks = 0; ks < 2; ++ks)
      #pragma unroll
      for (int n = 0; n < 4; ++n)
        vf[ks][n] = *reinterpret_cast<const short8*>(
            vbase + (size_t)(n * 16 + lr) * L_SEQ + kt * 64 + ks * 32 + lg * 8);

    // S = Q @ K^T
    f32x4 sacc[4];
    #pragma unroll
    for (int n = 0; n < 4; ++n) sacc[n] = f32x4{0.f, 0.f, 0.f, 0.f};
    #pragma unroll
    for (int ks = 0; ks < 2; ++ks) {
      #pragma unroll
      for (int n = 0; n < 4; ++n) {
        const int krow = n * 16 + lr;
        short8 kf = *reinterpret_cast<const short8*>(
            &Ks[cur][krow * 64 + (((ks * 4 + lg) ^ (krow & 7)) * 8)]);
        sacc[n] = __builtin_amdgcn_mfma_f32_16x16x32_bf16(qf[ks], kf, sacc[n], 0, 0, 0);
      }
    }

    // softcap: 50*tanh(S*0.125/50); |x|<=0.16 -> x(1 - x^2/3 + 2x^4/15)
    // base-2 with fixed shift -16 (capped logits in [-50,50] => safe)
    const int k0 = kt * 64;
    float p[4][4];
    #pragma unroll
    for (int n = 0; n < 4; ++n) {
      #pragma unroll
      for (int r = 0; r < 4; ++r) {
        const float xs = sacc[n][r];
        const float u = xs * xs * 6.25e-6f;
        const float poly = fmaf(u, fmaf(u, 0.13333333f, -0.33333333f), 1.0f);
        p[n][r] = fmaf(xs * 0.18033688f, poly, -16.0f);  // 0.125*log2(e)
      }
    }
    if (causal && (k0 + 63 > row0)) {  // diagonal tile only (kt == qt)
      #pragma unroll
      for (int n = 0; n < 4; ++n) {
        const int key = k0 + n * 16 + lr;
        #pragma unroll
        for (int r = 0; r < 4; ++r)
          if (key > row0 + lg * 4 + r) p[n][r] = -1e30f;
      }
    }
    // p = exp2(sv2), accumulate per-lane denom, write P to LDS (swizzled)
    #pragma unroll
    for (int n = 0; n < 4; ++n) {
      #pragma unroll
      for (int r = 0; r < 4; ++r) {
        const float pv = EXP2(p[n][r]);
        plt[r] += pv;
        const int prow = lg * 4 + r;
        const int key = n * 16 + lr;
        Ps[w * 1024 + prow * 64 + (((key >> 3) ^ (prow & 7)) * 8) + (key & 7)] =
            __float2bfloat16(pv);
      }
    }

    // O += P @ V (same-wave LDS readback, no barrier needed)
    #pragma unroll
    for (int ks = 0; ks < 2; ++ks) {
      short8 pf = *reinterpret_cast<const short8*>(
          &Ps[w * 1024 + lr * 64 + (((ks * 4 + lg) ^ (lr & 7)) * 8)]);
      #pragma unroll
      for (int n = 0; n < 4; ++n)
        oacc[n] = __builtin_amdgcn_mfma_f32_16x16x32_bf16(pf, vf[ks][n], oacc[n], 0, 0, 0);
    }
    cur ^= 1;
  }

  // epilogue: write partial denominators (f32) + un-normalized O (bf16)
  #pragma unroll
  for (int r = 0; r < 4; ++r) {
    float ls = plt[r];
    #pragma unroll
    for (int o = 1; o < 16; o <<= 1) ls += __shfl_xor(ls, o, 64);
    const int qg_ = row0 + lg * 4 + r;
    if (lr == 0)
      pd[((size_t)chunk * NB * NH + bh) * L_SEQ + qg_] = ls;
    #pragma unroll
    for (int n = 0; n < 4; ++n) {
      pO[((size_t)chunk * NB * L_SEQ + (size_t)b * L_SEQ + qg_) * DM + h * HDIM + n * 16 + lr] =
          __float2bfloat16(oacc[n][r]);
    }
  }
}

// ---------------- combine: y = sum_c O_c / sum_c d_c, bf16 ----------------
__global__ __launch_bounds__(256) void k_combine(const bf16* __restrict__ pO,
                                                 const float* __restrict__ pd,
                                                 bf16* __restrict__ y,
                                                 const int* __restrict__ causal_flag) {
  const int row = blockIdx.x;           // b*2048 + l
  const int b = row >> 11, l = row & 2047;
  const int qt = l >> 6;
  const bool causal = (*causal_flag) != 0;
  const int nkt = causal ? (qt + 1) : 32;
  const int nch = (nkt + CH - 1) / CH;  // valid chunk slots
  const int c4 = threadIdx.x * 4;       // col group of 4
  const int h = c4 >> 6;
  float den = 0.f;
  float a0 = 0.f, a1 = 0.f, a2 = 0.f, a3 = 0.f;
  for (int c = 0; c < nch; ++c) {
    den += pd[((size_t)c * NB * NH + b * NH + h) * L_SEQ + l];
    const size_t base = ((size_t)c * NB * L_SEQ + row) * DM + c4;
    ushort4 v = *reinterpret_cast<const ushort4*>(reinterpret_cast<const ushort*>(pO) + base);
    a0 += bs2f(v.x); a1 += bs2f(v.y); a2 += bs2f(v.z); a3 += bs2f(v.w);
  }
  const float inv = __builtin_amdgcn_rcpf(den);
  ushort4 o;
  o.x = f2bs(a0 * inv);
  o.y = f2bs(a1 * inv);
  o.z = f2bs(a2 * inv);
  o.w = f2bs(a3 * inv);
  *reinterpret_cast<ushort4*>(reinterpret_cast<ushort*>(y) + (size_t)row * DM + c4) = o;
}

extern "C" void kernel_launch(void* const* d_in, const int* in_sizes, int n_in,
                              void* d_out, int out_size, void* d_ws, size_t ws_size,
                              hipStream_t stream) {
  (void)in_sizes; (void)n_in; (void)out_size; (void)ws_size;
  const float* x  = (const float*)d_in[0];
  const float* Wq = (const float*)d_in[1];
  const float* bq = (const float*)d_in[2];
  const float* Wk = (const float*)d_in[3];
  const float* bk = (const float*)d_in[4];
  const float* Wv = (const float*)d_in[5];
  const float* bv = (const float*)d_in[6];
  const float* Wo = (const float*)d_in[7];
  const float* bo = (const float*)d_in[8];
  const float* qg = (const float*)d_in[9];
  const float* kg = (const float*)d_in[10];
  const float* rc = (const float*)d_in[11];
  const float* rs = (const float*)d_in[12];
  const int* causal = (const int*)d_in[13];
  float* out = (float*)d_out;

  char* ws = (char*)d_ws;
  size_t off = 0;
  auto alloc = [&](size_t bytes) -> char* {
    char* p = ws + off;
    off += (bytes + 255) & ~(size_t)255;
    return p;
  };
  bf16* xb   = (bf16*)alloc((size_t)4096 * 1024 * 2);
  bf16* wqt  = (bf16*)alloc((size_t)1024 * 1024 * 2);
  bf16* wkvt = (bf16*)alloc((size_t)512 * 1024 * 2);
  bf16* wot  = (bf16*)alloc((size_t)1024 * 1024 * 2);
  bf16* qp   = (bf16*)alloc((size_t)4096 * 1024 * 2);
  bf16* kp   = (bf16*)alloc((size_t)4096 * 256 * 2);
  bf16* vt   = (bf16*)alloc((size_t)NB * NKV * HDIM * L_SEQ * 2);
  bf16* qb   = (bf16*)alloc((size_t)NB * NH * L_SEQ * HDIM * 2);
  bf16* kb   = (bf16*)alloc((size_t)NB * NKV * L_SEQ * HDIM * 2);
  bf16* y    = (bf16*)alloc((size_t)4096 * 1024 * 2);
  bf16* pO   = (bf16*)alloc((size_t)NCHMAX * NB * L_SEQ * DM * 2);
  float* pd  = (float*)alloc((size_t)NCHMAX * NB * NH * L_SEQ * 4);
  bf16* wkt  = wkvt;
  bf16* wvt  = wkvt + (size_t)256 * 1024;

  k_cvt_x<<<4096, 256, 0, stream>>>(x, (ushort*)xb);
  k_transpose_all<<<dim3(32, 32, 4), dim3(32, 8), 0, stream>>>(Wq, Wk, Wv, Wo, wqt, wkt, wvt, wot);

  k_gemm<0><<<dim3(8, 64), 256, 0, stream>>>(xb, wqt, bq, nullptr, qp, nullptr, 4096, 1024, 1024);
  k_gemm<3><<<dim3(4, 64), 256, 0, stream>>>(xb, wkvt, bk, bv, kp, vt, 4096, 512, 1024);

  k_rmsrope<<<(NB * L_SEQ * 20) / 4, 256, 0, stream>>>(qp, kp, qg, kg, rc, rs, qb, kb);

  k_attn<<<dim3(32, NB * NH, NCHMAX), 256, 0, stream>>>(qb, kb, vt, pO, pd, causal);
  k_combine<<<NB * L_SEQ, 256, 0, stream>>>(pO, pd, y, causal);

  k_gemm<1><<<dim3(8, 64), 256, 0, stream>>>(y, wot, bo, nullptr, out, nullptr, 4096, 1024, 1024);
}

// Round 8
// 126.207 us; speedup vs baseline: 1.7590x; 1.7590x over previous
//
#include <hip/hip_runtime.h>
#include <hip/hip_bf16.h>

typedef __attribute__((ext_vector_type(8))) short short8;
typedef __attribute__((ext_vector_type(4))) float f32x4;

using bf16 = __hip_bfloat16;

#define L_SEQ 2048
#define NB 2
#define DM 1024
#define NH 16
#define NKV 4
#define HDIM 64
#define CAPV 50.0f

#if __has_builtin(__builtin_amdgcn_exp2f)
#define EXP2(x) __builtin_amdgcn_exp2f(x)
#else
#define EXP2(x) exp2f(x)
#endif

__device__ __forceinline__ unsigned short f2bs(float f) {
  bf16 h = __float2bfloat16(f);
  return __builtin_bit_cast(unsigned short, h);
}

__device__ __forceinline__ void gload_lds16(const void* g, void* l) {
  __builtin_amdgcn_global_load_lds(
      (const __attribute__((address_space(1))) void*)g,
      (__attribute__((address_space(3))) void*)l, 16, 0, 0);
}

// ---------------- x -> bf16 ----------------
__global__ void k_cvt_x(const float* __restrict__ x, ushort* __restrict__ xb) {
  int i = (blockIdx.x * blockDim.x + threadIdx.x) * 4;
  float4 v = *reinterpret_cast<const float4*>(x + i);
  ushort4 o = make_ushort4(f2bs(v.x), f2bs(v.y), f2bs(v.z), f2bs(v.w));
  *reinterpret_cast<ushort4*>(xb + i) = o;
}

// ---------------- all W[K][N] f32 -> Wt[N][K] bf16, one launch ----------------
__global__ void k_transpose_all(const float* __restrict__ Wq, const float* __restrict__ Wk,
                                const float* __restrict__ Wv, const float* __restrict__ Wo,
                                bf16* __restrict__ wqt, bf16* __restrict__ wkt,
                                bf16* __restrict__ wvt, bf16* __restrict__ wot) {
  __shared__ float tile[32][33];
  const int z = blockIdx.z;
  const float* W = (z == 0) ? Wq : (z == 1) ? Wk : (z == 2) ? Wv : Wo;
  bf16* Wt = (z == 0) ? wqt : (z == 1) ? wkt : (z == 2) ? wvt : wot;
  const int Ncols = (z == 1 || z == 2) ? 256 : 1024;
  const int bx = blockIdx.x * 32;
  if (bx >= Ncols) return;
  const int by = blockIdx.y * 32;
  const int tx = threadIdx.x, ty = threadIdx.y;
  #pragma unroll
  for (int j = 0; j < 32; j += 8)
    tile[ty + j][tx] = W[(size_t)(by + ty + j) * Ncols + bx + tx];
  __syncthreads();
  #pragma unroll
  for (int j = 0; j < 32; j += 8)
    Wt[(size_t)(bx + ty + j) * 1024 + by + tx] = __float2bfloat16(tile[tx][ty + j]);
}

// ---------------- GEMM: C[M,N] = A[M,K] @ Bt[N,K]^T + bias ----------------
// BM=64, BN=128, BK=64. LDS granule-XOR swizzled (pre-swizzled gload src).
// OUT_MODE: 0 = bf16 row-major, 1 = f32 row-major, 2 = bf16 transposed Vt,
//           3 = fused KV: col<256 -> kp row-major (bias), col>=256 -> Vt (bias2)
template<int OUT_MODE>
__global__ __launch_bounds__(256) void k_gemm(const bf16* __restrict__ A,
                                              const bf16* __restrict__ Bt,
                                              const float* __restrict__ bias,
                                              const float* __restrict__ bias2,
                                              void* __restrict__ Cout,
                                              void* __restrict__ Cout2,
                                              int M, int Ncols, int K) {
  __shared__ __align__(16) bf16 As[64 * 64];
  __shared__ __align__(16) bf16 Bs[128 * 64];
  const int t = threadIdx.x;
  const int lane = t & 63;
  const int w = t >> 6;
  const int wr = w >> 1, wc = w & 1;
  const int m0 = blockIdx.y * 64, n0 = blockIdx.x * 128;
  const int lr = lane & 15, lg = lane >> 4;

  f32x4 acc[2][4];
  #pragma unroll
  for (int m = 0; m < 2; ++m)
    #pragma unroll
    for (int n = 0; n < 4; ++n)
      acc[m][n] = f32x4{0.f, 0.f, 0.f, 0.f};

  for (int kt = 0; kt < K; kt += 64) {
    #pragma unroll
    for (int p = 0; p < 2; ++p) {
      const int Gb = p * 256 + w * 64;
      const int G = Gb + lane;
      const int row = G >> 3, gc = G & 7;
      gload_lds16(&A[(size_t)(m0 + row) * K + kt + ((gc ^ (row & 7)) * 8)], &As[Gb * 8]);
    }
    #pragma unroll
    for (int p = 0; p < 4; ++p) {
      const int Gb = p * 256 + w * 64;
      const int G = Gb + lane;
      const int row = G >> 3, gc = G & 7;
      gload_lds16(&Bt[(size_t)(n0 + row) * K + kt + ((gc ^ (row & 7)) * 8)], &Bs[Gb * 8]);
    }
    __syncthreads();
    #pragma unroll
    for (int ks = 0; ks < 2; ++ks) {
      short8 af[2], bfr[4];
      #pragma unroll
      for (int m = 0; m < 2; ++m) {
        const int row = wr * 32 + m * 16 + lr;
        af[m] = *reinterpret_cast<const short8*>(&As[row * 64 + (((ks * 4 + lg) ^ (row & 7)) * 8)]);
      }
      #pragma unroll
      for (int n = 0; n < 4; ++n) {
        const int row = wc * 64 + n * 16 + lr;
        bfr[n] = *reinterpret_cast<const short8*>(&Bs[row * 64 + (((ks * 4 + lg) ^ (row & 7)) * 8)]);
      }
      #pragma unroll
      for (int m = 0; m < 2; ++m)
        #pragma unroll
        for (int n = 0; n < 4; ++n)
          acc[m][n] = __builtin_amdgcn_mfma_f32_16x16x32_bf16(af[m], bfr[n], acc[m][n], 0, 0, 0);
    }
    __syncthreads();
  }

  #pragma unroll
  for (int m = 0; m < 2; ++m) {
    const int row = m0 + wr * 32 + m * 16 + lg * 4;
    #pragma unroll
    for (int n = 0; n < 4; ++n) {
      const int col = n0 + wc * 64 + n * 16 + lr;
      if (OUT_MODE == 2) {
        const float bv = bias[col];
        const int bb = row >> 11, l = row & 2047;
        ushort4 o;
        o.x = f2bs(acc[m][n][0] + bv);
        o.y = f2bs(acc[m][n][1] + bv);
        o.z = f2bs(acc[m][n][2] + bv);
        o.w = f2bs(acc[m][n][3] + bv);
        *reinterpret_cast<ushort4*>(
            &reinterpret_cast<bf16*>(Cout)[((size_t)bb * 256 + col) * L_SEQ + l]) = o;
      } else if (OUT_MODE == 3) {
        if (col < 256) {  // block-uniform branch (n0 in {0,128})
          const float bv = bias[col];
          #pragma unroll
          for (int r = 0; r < 4; ++r)
            reinterpret_cast<bf16*>(Cout)[(size_t)(row + r) * 256 + col] =
                __float2bfloat16(acc[m][n][r] + bv);
        } else {
          const int d = col - 256;
          const float bv = bias2[d];
          const int bb = row >> 11, l = row & 2047;
          ushort4 o;
          o.x = f2bs(acc[m][n][0] + bv);
          o.y = f2bs(acc[m][n][1] + bv);
          o.z = f2bs(acc[m][n][2] + bv);
          o.w = f2bs(acc[m][n][3] + bv);
          *reinterpret_cast<ushort4*>(
              &reinterpret_cast<bf16*>(Cout2)[((size_t)bb * 256 + d) * L_SEQ + l]) = o;
        }
      } else {
        const float bv = bias[col];
        #pragma unroll
        for (int r = 0; r < 4; ++r) {
          const float v = acc[m][n][r] + bv;
          if (OUT_MODE == 1)
            reinterpret_cast<float*>(Cout)[(size_t)(row + r) * Ncols + col] = v;
          else
            reinterpret_cast<bf16*>(Cout)[(size_t)(row + r) * Ncols + col] = __float2bfloat16(v);
        }
      }
    }
  }
}

// ---------------- RMSNorm + RoPE + layout (b,h,l,d) for q,k ----------------
__global__ __launch_bounds__(256) void k_rmsrope(
    const bf16* __restrict__ qp, const bf16* __restrict__ kp,
    const float* __restrict__ qg, const float* __restrict__ kg,
    const float* __restrict__ rc, const float* __restrict__ rs,
    bf16* __restrict__ qb, bf16* __restrict__ kb) {
  const int slot = blockIdx.x * 4 + (threadIdx.x >> 6);
  const int lane = threadIdx.x & 63;
  const int b = slot / (L_SEQ * 20);
  const int rem = slot % (L_SEQ * 20);
  const int l = rem / 20;
  const int s = rem % 20;

  const bool isq = (s < 16);
  const int h = isq ? s : s - 16;
  const bf16* src = isq ? qp : kp;
  const int cols = isq ? NH * HDIM : NKV * HDIM;
  float val = __bfloat162float(src[((size_t)b * L_SEQ + l) * cols + h * HDIM + lane]);
  float ss = val * val;
  #pragma unroll
  for (int o = 1; o < 64; o <<= 1) ss += __shfl_xor(ss, o, 64);
  const float inv = rsqrtf(ss * (1.0f / 64.0f) + 1e-6f);
  const float* g = isq ? qg : kg;
  const float tv = val * inv * g[h * HDIM + lane];
  const float partner = __shfl_xor(tv, 32, 64);
  const float rot = (lane < 32) ? -partner : partner;
  const float out = tv * rc[l * HDIM + lane] + rot * rs[l * HDIM + lane];
  bf16* dst = isq ? qb : kb;
  const int heads = isq ? NH : NKV;
  dst[(((size_t)b * heads + h) * L_SEQ + l) * HDIM + lane] = __float2bfloat16(out);
}

// ---------------- Flash attention: uniform-paired, K+V LDS double-buffered ---
// Uniform work per block (pair qt, 31-qt => 33 iters) avoids dispatcher
// clustering of heavy blocks (r5-r7 lesson). K AND V staged via gload_lds
// (swizzled source, linear dest) so PV reads are conflict-free ds_read_b128
// instead of 4x-duplicated scattered global loads.
__global__ __launch_bounds__(256) void k_attn(
    const bf16* __restrict__ qb, const bf16* __restrict__ kb,
    const bf16* __restrict__ vt, bf16* __restrict__ y,
    const int* __restrict__ causal_flag) {
  __shared__ __align__(16) bf16 Ks[2][64 * 64];
  __shared__ __align__(16) bf16 Vs[2][64 * 64];
  __shared__ __align__(16) bf16 Ps[4 * 16 * 64];

  const int t = threadIdx.x, lane = t & 63, w = t >> 6;
  const int lr = lane & 15, lg = lane >> 4;
  const int bh = blockIdx.y;
  const int b = bh >> 4, h = bh & 15;
  const int kvh = h >> 2;
  const bool causal = (*causal_flag) != 0;

  const bf16* kbase = kb + ((size_t)b * NKV + kvh) * L_SEQ * HDIM;
  const bf16* vbase = vt + ((size_t)b * NKV + kvh) * HDIM * L_SEQ;

  for (int seg = 0; seg < 2; ++seg) {
    const int qt = (seg == 0) ? (int)blockIdx.x : 31 - (int)blockIdx.x;
    const int q0 = qt * 64;
    const int nkt = causal ? (qt + 1) : 32;
    const int row0 = q0 + w * 16;

    const bf16* qrow = qb + (((size_t)bh) * L_SEQ + row0 + lr) * HDIM;
    short8 qf0 = *reinterpret_cast<const short8*>(qrow + lg * 8);
    short8 qf1 = *reinterpret_cast<const short8*>(qrow + 32 + lg * 8);

    f32x4 oacc[4];
    #pragma unroll
    for (int n = 0; n < 4; ++n) oacc[n] = f32x4{0.f, 0.f, 0.f, 0.f};
    float plt[4];
    #pragma unroll
    for (int r = 0; r < 4; ++r) plt[r] = 0.f;

    __syncthreads();  // protect K/V LDS reuse across segments
    {
      #pragma unroll
      for (int i = 0; i < 2; ++i) {
        const int Gb = i * 256 + w * 64;
        const int G = Gb + lane;
        const int row = G >> 3, gc = G & 7;
        gload_lds16(kbase + (size_t)row * HDIM + ((gc ^ (row & 7)) * 8), &Ks[0][Gb * 8]);
        gload_lds16(vbase + (size_t)row * L_SEQ + ((gc ^ (row & 7)) * 8), &Vs[0][Gb * 8]);
      }
    }
    int cur = 0;

    for (int kt = 0; kt < nkt; ++kt) {
      __syncthreads();  // buf[cur] ready (vmcnt drained by barrier semantics)

      if (kt + 1 < nkt) {
        const int k0n = (kt + 1) * 64;
        #pragma unroll
        for (int i = 0; i < 2; ++i) {
          const int Gb = i * 256 + w * 64;
          const int G = Gb + lane;
          const int row = G >> 3, gc = G & 7;
          gload_lds16(kbase + (size_t)(k0n + row) * HDIM + ((gc ^ (row & 7)) * 8),
                      &Ks[cur ^ 1][Gb * 8]);
          gload_lds16(vbase + (size_t)row * L_SEQ + k0n + ((gc ^ (row & 7)) * 8),
                      &Vs[cur ^ 1][Gb * 8]);
        }
      }

      // S = Q @ K^T
      f32x4 sacc[4];
      #pragma unroll
      for (int n = 0; n < 4; ++n) sacc[n] = f32x4{0.f, 0.f, 0.f, 0.f};
      #pragma unroll
      for (int n = 0; n < 4; ++n) {
        const int krow = n * 16 + lr;
        short8 kf0 = *reinterpret_cast<const short8*>(
            &Ks[cur][krow * 64 + ((lg ^ (krow & 7)) * 8)]);
        short8 kf1 = *reinterpret_cast<const short8*>(
            &Ks[cur][krow * 64 + (((4 + lg) ^ (krow & 7)) * 8)]);
        sacc[n] = __builtin_amdgcn_mfma_f32_16x16x32_bf16(qf0, kf0, sacc[n], 0, 0, 0);
        sacc[n] = __builtin_amdgcn_mfma_f32_16x16x32_bf16(qf1, kf1, sacc[n], 0, 0, 0);
      }

      // softcap: 50*tanh(S*0.125/50) in base-2, fixed shift -16.
      // x = S/400, |x| small => tanh(x) ~ x*(1 - x^2/3)  (x^4 term dropped,
      // logit error <= ~6e-3, negligible vs softmax scale)
      const int k0 = kt * 64;
      float p[4][4];
      #pragma unroll
      for (int n = 0; n < 4; ++n) {
        #pragma unroll
        for (int r = 0; r < 4; ++r) {
          const float xs = sacc[n][r];
          const float poly = fmaf(xs * xs, -2.0833333e-6f, 1.0f);
          p[n][r] = fmaf(xs * 0.18033688f, poly, -16.0f);  // 0.125*log2(e)*50tanh
        }
      }
      if (causal && (k0 + 63 > row0)) {  // wave-uniform: diagonal tile only
        #pragma unroll
        for (int n = 0; n < 4; ++n) {
          const int key = k0 + n * 16 + lr;
          #pragma unroll
          for (int r = 0; r < 4; ++r)
            if (key > row0 + lg * 4 + r) p[n][r] = -1e30f;
        }
      }
      // exp2, per-lane denom accumulate, P -> LDS (per-wave region, swizzled)
      #pragma unroll
      for (int n = 0; n < 4; ++n) {
        #pragma unroll
        for (int r = 0; r < 4; ++r) {
          const float pv = EXP2(p[n][r]);
          plt[r] += pv;
          const int prow = lg * 4 + r;
          const int key = n * 16 + lr;
          Ps[w * 1024 + prow * 64 + (((key >> 3) ^ (prow & 7)) * 8) + (key & 7)] =
              __float2bfloat16(pv);
        }
      }

      // O += P @ V (same-wave LDS readback; V frags from LDS, conflict-free)
      #pragma unroll
      for (int ks = 0; ks < 2; ++ks) {
        short8 pf = *reinterpret_cast<const short8*>(
            &Ps[w * 1024 + lr * 64 + (((ks * 4 + lg) ^ (lr & 7)) * 8)]);
        #pragma unroll
        for (int n = 0; n < 4; ++n) {
          const int vd = n * 16 + lr;
          short8 vfr = *reinterpret_cast<const short8*>(
              &Vs[cur][vd * 64 + (((ks * 4 + lg) ^ (vd & 7)) * 8)]);
          oacc[n] = __builtin_amdgcn_mfma_f32_16x16x32_bf16(pf, vfr, oacc[n], 0, 0, 0);
        }
      }
      cur ^= 1;
    }

    // epilogue: single denom reduce, then write
    #pragma unroll
    for (int r = 0; r < 4; ++r) {
      float ls = plt[r];
      #pragma unroll
      for (int o = 1; o < 16; o <<= 1) ls += __shfl_xor(ls, o, 64);
      const float invl = __builtin_amdgcn_rcpf(ls);
      const int qg_ = row0 + lg * 4 + r;
      #pragma unroll
      for (int n = 0; n < 4; ++n) {
        y[((size_t)b * L_SEQ + qg_) * DM + h * HDIM + n * 16 + lr] =
            __float2bfloat16(oacc[n][r] * invl);
      }
    }
  }
}

extern "C" void kernel_launch(void* const* d_in, const int* in_sizes, int n_in,
                              void* d_out, int out_size, void* d_ws, size_t ws_size,
                              hipStream_t stream) {
  (void)in_sizes; (void)n_in; (void)out_size; (void)ws_size;
  const float* x  = (const float*)d_in[0];
  const float* Wq = (const float*)d_in[1];
  const float* bq = (const float*)d_in[2];
  const float* Wk = (const float*)d_in[3];
  const float* bk = (const float*)d_in[4];
  const float* Wv = (const float*)d_in[5];
  const float* bv = (const float*)d_in[6];
  const float* Wo = (const float*)d_in[7];
  const float* bo = (const float*)d_in[8];
  const float* qg = (const float*)d_in[9];
  const float* kg = (const float*)d_in[10];
  const float* rc = (const float*)d_in[11];
  const float* rs = (const float*)d_in[12];
  const int* causal = (const int*)d_in[13];
  float* out = (float*)d_out;

  char* ws = (char*)d_ws;
  size_t off = 0;
  auto alloc = [&](size_t bytes) -> char* {
    char* p = ws + off;
    off += (bytes + 255) & ~(size_t)255;
    return p;
  };
  bf16* xb   = (bf16*)alloc((size_t)4096 * 1024 * 2);
  bf16* wqt  = (bf16*)alloc((size_t)1024 * 1024 * 2);
  bf16* wkvt = (bf16*)alloc((size_t)512 * 1024 * 2);
  bf16* wot  = (bf16*)alloc((size_t)1024 * 1024 * 2);
  bf16* qp   = (bf16*)alloc((size_t)4096 * 1024 * 2);
  bf16* kp   = (bf16*)alloc((size_t)4096 * 256 * 2);
  bf16* vt   = (bf16*)alloc((size_t)NB * NKV * HDIM * L_SEQ * 2);
  bf16* qb   = (bf16*)alloc((size_t)NB * NH * L_SEQ * HDIM * 2);
  bf16* kb   = (bf16*)alloc((size_t)NB * NKV * L_SEQ * HDIM * 2);
  bf16* y    = (bf16*)alloc((size_t)4096 * 1024 * 2);
  bf16* wkt  = wkvt;
  bf16* wvt  = wkvt + (size_t)256 * 1024;

  k_cvt_x<<<4096, 256, 0, stream>>>(x, (ushort*)xb);
  k_transpose_all<<<dim3(32, 32, 4), dim3(32, 8), 0, stream>>>(Wq, Wk, Wv, Wo, wqt, wkt, wvt, wot);

  k_gemm<0><<<dim3(8, 64), 256, 0, stream>>>(xb, wqt, bq, nullptr, qp, nullptr, 4096, 1024, 1024);
  k_gemm<3><<<dim3(4, 64), 256, 0, stream>>>(xb, wkvt, bk, bv, kp, vt, 4096, 512, 1024);

  k_rmsrope<<<(NB * L_SEQ * 20) / 4, 256, 0, stream>>>(qp, kp, qg, kg, rc, rs, qb, kb);

  k_attn<<<dim3(16, NB * NH), 256, 0, stream>>>(qb, kb, vt, y, causal);

  k_gemm<1><<<dim3(8, 64), 256, 0, stream>>>(y, wot, bo, nullptr, out, nullptr, 4096, 1024, 1024);
}

// Round 10
// 118.784 us; speedup vs baseline: 1.8689x; 1.0625x over previous
//
#include <hip/hip_runtime.h>
#include <hip/hip_bf16.h>

typedef __attribute__((ext_vector_type(8))) short short8;
typedef __attribute__((ext_vector_type(4))) float f32x4;

using bf16 = __hip_bfloat16;

#define L_SEQ 2048
#define NB 2
#define DM 1024
#define NH 16
#define NKV 4
#define HDIM 64
#define CAPV 50.0f

#if __has_builtin(__builtin_amdgcn_exp2f)
#define EXP2(x) __builtin_amdgcn_exp2f(x)
#else
#define EXP2(x) exp2f(x)
#endif

__device__ __forceinline__ unsigned short f2bs(float f) {
  bf16 h = __float2bfloat16(f);
  return __builtin_bit_cast(unsigned short, h);
}

__device__ __forceinline__ float bs2f(unsigned short u) {
  return __bfloat162float(__builtin_bit_cast(bf16, u));
}

__device__ __forceinline__ void gload_lds16(const void* g, void* l) {
  __builtin_amdgcn_global_load_lds(
      (const __attribute__((address_space(1))) void*)g,
      (__attribute__((address_space(3))) void*)l, 16, 0, 0);
}

// ---------------- x -> bf16 ----------------
__global__ void k_cvt_x(const float* __restrict__ x, ushort* __restrict__ xb) {
  int i = (blockIdx.x * blockDim.x + threadIdx.x) * 4;
  float4 v = *reinterpret_cast<const float4*>(x + i);
  ushort4 o = make_ushort4(f2bs(v.x), f2bs(v.y), f2bs(v.z), f2bs(v.w));
  *reinterpret_cast<ushort4*>(xb + i) = o;
}

// ---------------- all W[K][N] f32 -> Wt[N][K] bf16, one launch ----------------
__global__ void k_transpose_all(const float* __restrict__ Wq, const float* __restrict__ Wk,
                                const float* __restrict__ Wv, const float* __restrict__ Wo,
                                bf16* __restrict__ wqt, bf16* __restrict__ wkt,
                                bf16* __restrict__ wvt, bf16* __restrict__ wot) {
  __shared__ float tile[32][33];
  const int z = blockIdx.z;
  const float* W = (z == 0) ? Wq : (z == 1) ? Wk : (z == 2) ? Wv : Wo;
  bf16* Wt = (z == 0) ? wqt : (z == 1) ? wkt : (z == 2) ? wvt : wot;
  const int Ncols = (z == 1 || z == 2) ? 256 : 1024;
  const int bx = blockIdx.x * 32;
  if (bx >= Ncols) return;
  const int by = blockIdx.y * 32;
  const int tx = threadIdx.x, ty = threadIdx.y;
  #pragma unroll
  for (int j = 0; j < 32; j += 8)
    tile[ty + j][tx] = W[(size_t)(by + ty + j) * Ncols + bx + tx];
  __syncthreads();
  #pragma unroll
  for (int j = 0; j < 32; j += 8)
    Wt[(size_t)(bx + ty + j) * 1024 + by + tx] = __float2bfloat16(tile[tx][ty + j]);
}

// ---------------- GEMM: C[M,N] = A[M,K] @ Bt[N,K]^T + bias ----------------
// BM=64, BN=128, BK=64. LDS granule-XOR swizzled (pre-swizzled gload src).
// OUT_MODE: 1 = f32 row-major (Wo)
//           4 = Q proj: fused bias+RMSNorm+RoPE -> qb (b,h,l,d)
//           5 = fused KV: col<256 -> K fused rms+rope -> kb; col>=256 -> Vt
template<int OUT_MODE>
__global__ __launch_bounds__(256) void k_gemm(const bf16* __restrict__ A,
                                              const bf16* __restrict__ Bt,
                                              const float* __restrict__ bias,
                                              const float* __restrict__ bias2,
                                              const float* __restrict__ gma,
                                              const float* __restrict__ rcT,
                                              const float* __restrict__ rsT,
                                              void* __restrict__ Cout,
                                              void* __restrict__ Cout2,
                                              int M, int Ncols, int K) {
  __shared__ __align__(16) bf16 As[64 * 64];
  __shared__ __align__(16) bf16 Bs[128 * 64];
  const int t = threadIdx.x;
  const int lane = t & 63;
  const int w = t >> 6;
  const int wr = w >> 1, wc = w & 1;
  const int m0 = blockIdx.y * 64, n0 = blockIdx.x * 128;
  const int lr = lane & 15, lg = lane >> 4;

  f32x4 acc[2][4];
  #pragma unroll
  for (int m = 0; m < 2; ++m)
    #pragma unroll
    for (int n = 0; n < 4; ++n)
      acc[m][n] = f32x4{0.f, 0.f, 0.f, 0.f};

  for (int kt = 0; kt < K; kt += 64) {
    #pragma unroll
    for (int p = 0; p < 2; ++p) {
      const int Gb = p * 256 + w * 64;
      const int G = Gb + lane;
      const int row = G >> 3, gc = G & 7;
      gload_lds16(&A[(size_t)(m0 + row) * K + kt + ((gc ^ (row & 7)) * 8)], &As[Gb * 8]);
    }
    #pragma unroll
    for (int p = 0; p < 4; ++p) {
      const int Gb = p * 256 + w * 64;
      const int G = Gb + lane;
      const int row = G >> 3, gc = G & 7;
      gload_lds16(&Bt[(size_t)(n0 + row) * K + kt + ((gc ^ (row & 7)) * 8)], &Bs[Gb * 8]);
    }
    __syncthreads();
    #pragma unroll
    for (int ks = 0; ks < 2; ++ks) {
      short8 af[2], bfr[4];
      #pragma unroll
      for (int m = 0; m < 2; ++m) {
        const int row = wr * 32 + m * 16 + lr;
        af[m] = *reinterpret_cast<const short8*>(&As[row * 64 + (((ks * 4 + lg) ^ (row & 7)) * 8)]);
      }
      #pragma unroll
      for (int n = 0; n < 4; ++n) {
        const int row = wc * 64 + n * 16 + lr;
        bfr[n] = *reinterpret_cast<const short8*>(&Bs[row * 64 + (((ks * 4 + lg) ^ (row & 7)) * 8)]);
      }
      #pragma unroll
      for (int m = 0; m < 2; ++m)
        #pragma unroll
        for (int n = 0; n < 4; ++n)
          acc[m][n] = __builtin_amdgcn_mfma_f32_16x16x32_bf16(af[m], bfr[n], acc[m][n], 0, 0, 0);
    }
    __syncthreads();
  }

  const int colbase = n0 + wc * 64;  // wave-uniform, 64-col span = one head

  if (OUT_MODE == 1) {
    #pragma unroll
    for (int m = 0; m < 2; ++m) {
      const int row = m0 + wr * 32 + m * 16 + lg * 4;
      #pragma unroll
      for (int n = 0; n < 4; ++n) {
        const int col = colbase + n * 16 + lr;
        const float bv = bias[col];
        #pragma unroll
        for (int r = 0; r < 4; ++r)
          reinterpret_cast<float*>(Cout)[(size_t)(row + r) * Ncols + col] = acc[m][n][r] + bv;
      }
    }
  } else if (OUT_MODE == 5 && colbase >= 256) {
    // V: bf16 transposed Vt[b][d][l]
    #pragma unroll
    for (int m = 0; m < 2; ++m) {
      const int row = m0 + wr * 32 + m * 16 + lg * 4;
      const int bb = row >> 11, l = row & 2047;
      #pragma unroll
      for (int n = 0; n < 4; ++n) {
        const int d = colbase + n * 16 + lr - 256;
        const float bv = bias2[d];
        ushort4 o;
        o.x = f2bs(acc[m][n][0] + bv);
        o.y = f2bs(acc[m][n][1] + bv);
        o.z = f2bs(acc[m][n][2] + bv);
        o.w = f2bs(acc[m][n][3] + bv);
        *reinterpret_cast<ushort4*>(
            &reinterpret_cast<bf16*>(Cout2)[((size_t)bb * 256 + d) * L_SEQ + l]) = o;
      }
    }
  } else {
    // fused bias + RMSNorm + RoPE (Q or K), write (b, head, l, d)
    const int head = colbase >> 6;
    const int heads = (OUT_MODE == 4) ? NH : NKV;
    float g[4];
    #pragma unroll
    for (int n = 0; n < 4; ++n) g[n] = gma[colbase + n * 16 + lr];
    #pragma unroll
    for (int m = 0; m < 2; ++m) {
      const int row = m0 + wr * 32 + m * 16 + lg * 4;
      float vv[4][4];
      float ss[4] = {0.f, 0.f, 0.f, 0.f};
      #pragma unroll
      for (int n = 0; n < 4; ++n) {
        const float bv = bias[colbase + n * 16 + lr];
        #pragma unroll
        for (int r = 0; r < 4; ++r) {
          vv[n][r] = acc[m][n][r] + bv;
          ss[r] = fmaf(vv[n][r], vv[n][r], ss[r]);
        }
      }
      #pragma unroll
      for (int r = 0; r < 4; ++r) {
        float s = ss[r];
        s += __shfl_xor(s, 1, 64);
        s += __shfl_xor(s, 2, 64);
        s += __shfl_xor(s, 4, 64);
        s += __shfl_xor(s, 8, 64);
        ss[r] = rsqrtf(s * (1.0f / 64.0f) + 1e-6f);
      }
      float tv[4][4];
      #pragma unroll
      for (int n = 0; n < 4; ++n)
        #pragma unroll
        for (int r = 0; r < 4; ++r)
          tv[n][r] = vv[n][r] * ss[r] * g[n];
      #pragma unroll
      for (int r = 0; r < 4; ++r) {
        const int grow = row + r;
        const int bb = grow >> 11, l = grow & 2047;
        bf16* dst = reinterpret_cast<bf16*>(Cout) +
                    (((size_t)bb * heads + head) * L_SEQ + l) * HDIM;
        #pragma unroll
        for (int n = 0; n < 4; ++n) {
          const int d = n * 16 + lr;
          const float c = rcT[l * HDIM + d];
          const float s2 = rsT[l * HDIM + d];
          const float rot = (n < 2) ? -tv[n ^ 2][r] : tv[n ^ 2][r];
          dst[d] = __float2bfloat16(fmaf(tv[n][r], c, rot * s2));
        }
      }
    }
  }
}

// ---------------- Flash attention: uniform split-half, K+V LDS dbuf ----------
// Pair x: seg0 = q-tile x (t_a tiles), seg1 = q-tile 31-x (t_b tiles).
// Merged sequence split at mid=(t_a+t_b+1)/2: half0=[0,mid), half1=[mid,total).
// Uniform work (17/16 tiles causal, 32/32 non-causal); 1024 blocks = 4/CU.
// Segs whose range is complete write y directly; partial segs write bf16
// O-numerator + f32 denominator (fixed-shift softmax => linear).
__global__ __launch_bounds__(256) void k_attn(
    const bf16* __restrict__ qb, const bf16* __restrict__ kb,
    const bf16* __restrict__ vt, bf16* __restrict__ y,
    bf16* __restrict__ pO, float* __restrict__ pd,
    const int* __restrict__ causal_flag) {
  __shared__ __align__(16) bf16 Ks[2][64 * 64];
  __shared__ __align__(16) bf16 Vs[2][64 * 64];
  __shared__ __align__(16) bf16 Ps[4 * 16 * 64];

  const int t = threadIdx.x, lane = t & 63, w = t >> 6;
  const int lr = lane & 15, lg = lane >> 4;
  const int x = blockIdx.x;
  const int bh = blockIdx.y;
  const int half = blockIdx.z;
  const int b = bh >> 4, h = bh & 15;
  const int kvh = h >> 2;
  const bool causal = (*causal_flag) != 0;

  const int t_a = causal ? (x + 1) : 32;
  const int t_b = causal ? (32 - x) : 32;
  const int total = t_a + t_b;
  const int mid = (total + 1) >> 1;
  const int g0 = half ? mid : 0;
  const int g1 = half ? total : mid;

  const bf16* kbase = kb + ((size_t)b * NKV + kvh) * L_SEQ * HDIM;
  const bf16* vbase = vt + ((size_t)b * NKV + kvh) * HDIM * L_SEQ;

  #pragma unroll
  for (int seg = 0; seg < 2; ++seg) {
    const int qt = seg ? (31 - x) : x;
    const int ts = seg ? t_b : t_a;
    const int base = seg ? t_a : 0;
    const int lo = max(0, g0 - base);
    const int hi = min(ts, g1 - base);
    if (lo >= hi) continue;                 // block-uniform

    const int q0 = qt * 64;
    const int row0 = q0 + w * 16;

    const bf16* qrow = qb + (((size_t)bh) * L_SEQ + row0 + lr) * HDIM;
    short8 qf0 = *reinterpret_cast<const short8*>(qrow + lg * 8);
    short8 qf1 = *reinterpret_cast<const short8*>(qrow + 32 + lg * 8);

    f32x4 oacc[4];
    #pragma unroll
    for (int n = 0; n < 4; ++n) oacc[n] = f32x4{0.f, 0.f, 0.f, 0.f};
    float plt[4];
    #pragma unroll
    for (int r = 0; r < 4; ++r) plt[r] = 0.f;

    __syncthreads();  // protect K/V LDS reuse across segments
    {
      const int k00 = lo * 64;
      #pragma unroll
      for (int i = 0; i < 2; ++i) {
        const int Gb = i * 256 + w * 64;
        const int G = Gb + lane;
        const int row = G >> 3, gc = G & 7;
        gload_lds16(kbase + (size_t)(k00 + row) * HDIM + ((gc ^ (row & 7)) * 8), &Ks[0][Gb * 8]);
        gload_lds16(vbase + (size_t)row * L_SEQ + k00 + ((gc ^ (row & 7)) * 8), &Vs[0][Gb * 8]);
      }
    }
    int cur = 0;

    for (int kt = lo; kt < hi; ++kt) {
      __syncthreads();  // buf[cur] ready

      if (kt + 1 < hi) {
        const int k0n = (kt + 1) * 64;
        #pragma unroll
        for (int i = 0; i < 2; ++i) {
          const int Gb = i * 256 + w * 64;
          const int G = Gb + lane;
          const int row = G >> 3, gc = G & 7;
          gload_lds16(kbase + (size_t)(k0n + row) * HDIM + ((gc ^ (row & 7)) * 8),
                      &Ks[cur ^ 1][Gb * 8]);
          gload_lds16(vbase + (size_t)row * L_SEQ + k0n + ((gc ^ (row & 7)) * 8),
                      &Vs[cur ^ 1][Gb * 8]);
        }
      }

      // S = Q @ K^T
      f32x4 sacc[4];
      #pragma unroll
      for (int n = 0; n < 4; ++n) sacc[n] = f32x4{0.f, 0.f, 0.f, 0.f};
      #pragma unroll
      for (int n = 0; n < 4; ++n) {
        const int krow = n * 16 + lr;
        short8 kf0 = *reinterpret_cast<const short8*>(
            &Ks[cur][krow * 64 + ((lg ^ (krow & 7)) * 8)]);
        short8 kf1 = *reinterpret_cast<const short8*>(
            &Ks[cur][krow * 64 + (((4 + lg) ^ (krow & 7)) * 8)]);
        sacc[n] = __builtin_amdgcn_mfma_f32_16x16x32_bf16(qf0, kf0, sacc[n], 0, 0, 0);
        sacc[n] = __builtin_amdgcn_mfma_f32_16x16x32_bf16(qf1, kf1, sacc[n], 0, 0, 0);
      }

      // softcap 50*tanh(S/400) in base-2, fixed shift -16
      const int k0 = kt * 64;
      float p[4][4];
      #pragma unroll
      for (int n = 0; n < 4; ++n) {
        #pragma unroll
        for (int r = 0; r < 4; ++r) {
          const float xs = sacc[n][r];
          const float poly = fmaf(xs * xs, -2.0833333e-6f, 1.0f);
          p[n][r] = fmaf(xs * 0.18033688f, poly, -16.0f);
        }
      }
      if (causal && (k0 + 63 > row0)) {  // diagonal tile only
        #pragma unroll
        for (int n = 0; n < 4; ++n) {
          const int key = k0 + n * 16 + lr;
          #pragma unroll
          for (int r = 0; r < 4; ++r)
            if (key > row0 + lg * 4 + r) p[n][r] = -1e30f;
        }
      }
      #pragma unroll
      for (int n = 0; n < 4; ++n) {
        #pragma unroll
        for (int r = 0; r < 4; ++r) {
          const float pv = EXP2(p[n][r]);
          plt[r] += pv;
          const int prow = lg * 4 + r;
          const int key = n * 16 + lr;
          Ps[w * 1024 + prow * 64 + (((key >> 3) ^ (prow & 7)) * 8) + (key & 7)] =
              __float2bfloat16(pv);
        }
      }

      // O += P @ V
      #pragma unroll
      for (int ks = 0; ks < 2; ++ks) {
        short8 pf = *reinterpret_cast<const short8*>(
            &Ps[w * 1024 + lr * 64 + (((ks * 4 + lg) ^ (lr & 7)) * 8)]);
        #pragma unroll
        for (int n = 0; n < 4; ++n) {
          const int vd = n * 16 + lr;
          short8 vfr = *reinterpret_cast<const short8*>(
              &Vs[cur][vd * 64 + (((ks * 4 + lg) ^ (vd & 7)) * 8)]);
          oacc[n] = __builtin_amdgcn_mfma_f32_16x16x32_bf16(pf, vfr, oacc[n], 0, 0, 0);
        }
      }
      cur ^= 1;
    }

    // epilogue
    const bool full = (lo == 0) && (hi == ts);
    #pragma unroll
    for (int r = 0; r < 4; ++r) {
      float ls = plt[r];
      #pragma unroll
      for (int o = 1; o < 16; o <<= 1) ls += __shfl_xor(ls, o, 64);
      const int qg_ = row0 + lg * 4 + r;
      if (full) {
        const float invl = __builtin_amdgcn_rcpf(ls);
        #pragma unroll
        for (int n = 0; n < 4; ++n)
          y[((size_t)b * L_SEQ + qg_) * DM + h * HDIM + n * 16 + lr] =
              __float2bfloat16(oacc[n][r] * invl);
      } else {
        if (lr == 0)
          pd[((size_t)half * NB * NH + bh) * L_SEQ + qg_] = ls;
        #pragma unroll
        for (int n = 0; n < 4; ++n)
          pO[(((size_t)half * NB + b) * L_SEQ + qg_) * DM + h * HDIM + n * 16 + lr] =
              __float2bfloat16(oacc[n][r]);
      }
    }
  }
}

// ---------------- combine heavy rows (l >= 1024): y = (O0+O1)/(d0+d1) -------
__global__ __launch_bounds__(256) void k_combine(const bf16* __restrict__ pO,
                                                 const float* __restrict__ pd,
                                                 bf16* __restrict__ y,
                                                 const int* __restrict__ causal_flag) {
  if ((*causal_flag) == 0) return;  // non-causal: all rows direct-written
  const int b = blockIdx.x >> 10;
  const int l = 1024 + (blockIdx.x & 1023);
  const int c4 = threadIdx.x * 4;
  const int h = c4 >> 6;
  const float d0 = pd[((size_t)b * NH + h) * L_SEQ + l];
  const float d1 = pd[((size_t)NB * NH + b * NH + h) * L_SEQ + l];
  const float inv = __builtin_amdgcn_rcpf(d0 + d1);
  const size_t base0 = ((size_t)b * L_SEQ + l) * DM + c4;
  const size_t base1 = (((size_t)NB + b) * L_SEQ + l) * DM + c4;
  ushort4 a = *reinterpret_cast<const ushort4*>(reinterpret_cast<const ushort*>(pO) + base0);
  ushort4 bb = *reinterpret_cast<const ushort4*>(reinterpret_cast<const ushort*>(pO) + base1);
  ushort4 o;
  o.x = f2bs((bs2f(a.x) + bs2f(bb.x)) * inv);
  o.y = f2bs((bs2f(a.y) + bs2f(bb.y)) * inv);
  o.z = f2bs((bs2f(a.z) + bs2f(bb.z)) * inv);
  o.w = f2bs((bs2f(a.w) + bs2f(bb.w)) * inv);
  *reinterpret_cast<ushort4*>(reinterpret_cast<ushort*>(y) +
                              ((size_t)b * L_SEQ + l) * DM + c4) = o;
}

extern "C" void kernel_launch(void* const* d_in, const int* in_sizes, int n_in,
                              void* d_out, int out_size, void* d_ws, size_t ws_size,
                              hipStream_t stream) {
  (void)in_sizes; (void)n_in; (void)out_size; (void)ws_size;
  const float* x  = (const float*)d_in[0];
  const float* Wq = (const float*)d_in[1];
  const float* bq = (const float*)d_in[2];
  const float* Wk = (const float*)d_in[3];
  const float* bk = (const float*)d_in[4];
  const float* Wv = (const float*)d_in[5];
  const float* bv = (const float*)d_in[6];
  const float* Wo = (const float*)d_in[7];
  const float* bo = (const float*)d_in[8];
  const float* qg = (const float*)d_in[9];
  const float* kg = (const float*)d_in[10];
  const float* rc = (const float*)d_in[11];
  const float* rs = (const float*)d_in[12];
  const int* causal = (const int*)d_in[13];
  float* out = (float*)d_out;

  char* ws = (char*)d_ws;
  size_t off = 0;
  auto alloc = [&](size_t bytes) -> char* {
    char* p = ws + off;
    off += (bytes + 255) & ~(size_t)255;
    return p;
  };
  bf16* xb   = (bf16*)alloc((size_t)4096 * 1024 * 2);
  bf16* wqt  = (bf16*)alloc((size_t)1024 * 1024 * 2);
  bf16* wkvt = (bf16*)alloc((size_t)512 * 1024 * 2);
  bf16* wot  = (bf16*)alloc((size_t)1024 * 1024 * 2);
  bf16* vt   = (bf16*)alloc((size_t)NB * NKV * HDIM * L_SEQ * 2);
  bf16* qb   = (bf16*)alloc((size_t)NB * NH * L_SEQ * HDIM * 2);
  bf16* kb   = (bf16*)alloc((size_t)NB * NKV * L_SEQ * HDIM * 2);
  bf16* y    = (bf16*)alloc((size_t)4096 * 1024 * 2);
  bf16* pO   = (bf16*)alloc((size_t)2 * NB * L_SEQ * DM * 2);
  float* pd  = (float*)alloc((size_t)2 * NB * NH * L_SEQ * 4);
  bf16* wkt  = wkvt;
  bf16* wvt  = wkvt + (size_t)256 * 1024;

  k_cvt_x<<<4096, 256, 0, stream>>>(x, (ushort*)xb);
  k_transpose_all<<<dim3(32, 32, 4), dim3(32, 8), 0, stream>>>(Wq, Wk, Wv, Wo, wqt, wkt, wvt, wot);

  // Q projection with fused RMSNorm+RoPE -> qb
  k_gemm<4><<<dim3(8, 64), 256, 0, stream>>>(xb, wqt, bq, nullptr, qg, rc, rs,
                                             qb, nullptr, 4096, 1024, 1024);
  // KV projection: K fused RMSNorm+RoPE -> kb ; V -> Vt
  k_gemm<5><<<dim3(4, 64), 256, 0, stream>>>(xb, wkvt, bk, bv, kg, rc, rs,
                                             kb, vt, 4096, 512, 1024);

  k_attn<<<dim3(16, NB * NH, 2), 256, 0, stream>>>(qb, kb, vt, y, pO, pd, causal);
  k_combine<<<NB * 1024, 256, 0, stream>>>(pO, pd, y, causal);

  k_gemm<1><<<dim3(8, 64), 256, 0, stream>>>(y, wot, bo, nullptr, nullptr, nullptr, nullptr,
                                             out, nullptr, 4096, 1024, 1024);
}